// Round 10
// baseline (73.492 us; speedup 1.0000x reference)
//
#include <hip/hip_runtime.h>
#include <hip/hip_bf16.h>

typedef __bf16 bf16x8 __attribute__((ext_vector_type(8)));
typedef float  f32x4  __attribute__((ext_vector_type(4)));

#define LRELU_ALPHA 0.2f
#define LOG2E 1.44269504088896340736f

// native 2^x (single v_exp_f32, no OCML call)
__device__ __forceinline__ float fexp2(float x) {
#if __has_builtin(__builtin_amdgcn_exp2f)
    return __builtin_amdgcn_exp2f(x);
#else
    float r; asm("v_exp_f32 %0, %1" : "=v"(r) : "v"(x)); return r;
#endif
}

// ---------------------------------------------------------------------------
// Kernel 1: h = inp @ W (8 rows/block) -> hb (bf16), f1 = log2e*(h·a1),
// f2 = log2e*(h·a2).
// ---------------------------------------------------------------------------
__global__ __launch_bounds__(128) void gat_prep(
    const float* __restrict__ inp, const float* __restrict__ W,
    const float* __restrict__ a,
    __bf16* __restrict__ hb, float* __restrict__ f1, float* __restrict__ f2)
{
    const int r0 = blockIdx.x << 3;
    const int d  = threadIdx.x;
    __shared__ float sIn[8][128];
    __shared__ float sRed[8][4];
    #pragma unroll
    for (int r = 0; r < 8; ++r)
        sIn[r][d] = inp[(size_t)(r0 + r) * 128 + d];
    __syncthreads();

    float acc[8] = {0.f,0.f,0.f,0.f,0.f,0.f,0.f,0.f};
    #pragma unroll 4
    for (int k = 0; k < 128; ++k) {
        float wv = W[k * 128 + d];
        #pragma unroll
        for (int r = 0; r < 8; ++r) acc[r] += sIn[r][k] * wv;
    }

    const float a1 = a[d], a2 = a[128 + d];
    const int wv = d >> 6;
    #pragma unroll
    for (int r = 0; r < 8; ++r) {
        hb[(size_t)(r0 + r) * 128 + d] = (__bf16)acc[r];
        float t1 = acc[r] * a1;
        float t2 = acc[r] * a2;
        #pragma unroll
        for (int m = 1; m < 64; m <<= 1) {
            t1 += __shfl_xor(t1, m);
            t2 += __shfl_xor(t2, m);
        }
        if ((d & 63) == 0) { sRed[r][wv] = t1; sRed[r][2 + wv] = t2; }
    }
    __syncthreads();
    if (d < 8) {
        f1[r0 + d] = (sRed[d][0] + sRed[d][1]) * LOG2E;
        f2[r0 + d] = (sRed[d][2] + sRed[d][3]) * LOG2E;
    }
}

// ---------------------------------------------------------------------------
// Kernel 2: per-batch max of (prescaled) f1
// ---------------------------------------------------------------------------
__global__ __launch_bounds__(256) void gat_f1max(
    const float* __restrict__ f1, float* __restrict__ f1max)
{
    const int b = blockIdx.x;
    const int t = threadIdx.x;
    float m = -1e30f;
    for (int j = t; j < 2048; j += 256) m = fmaxf(m, f1[b * 2048 + j]);
    #pragma unroll
    for (int k = 1; k < 64; k <<= 1) m = fmaxf(m, __shfl_xor(m, k));
    __shared__ float sm[4];
    if ((t & 63) == 0) sm[t >> 6] = m;
    __syncthreads();
    if (t == 0) f1max[b] = fmaxf(fmaxf(sm[0], sm[1]), fmaxf(sm[2], sm[3]));
}

// ---------------------------------------------------------------------------
// Kernel 3: hb (bf16 [b][n][128]) -> pack: fragment-major bf16 B-operands.
// pack elem offset = (b*32 + jt)*8192 + frag*512 + lane*8, frag = D*2 + jh32.
// Fragment lane(il,kg) elem e = h[jt*64 + jh32*32 + kg*8 + e][D*16 + il].
// ---------------------------------------------------------------------------
__global__ __launch_bounds__(256) void gat_pack(
    const __bf16* __restrict__ hb, __bf16* __restrict__ pack)
{
    __shared__ __bf16 tile[64][72];
    const int tid = threadIdx.x;
    const int bidx = blockIdx.x;         // 512 blocks
    const int b  = bidx >> 6;
    const int tI = bidx & 63;
    const int n0 = (tI >> 1) << 6;       // j-range 64
    const int d0 = (tI & 1) << 6;        // d-range 64
    #pragma unroll
    for (int pass = 0; pass < 2; ++pass) {
        int row = (tid >> 3) + (pass << 5);
        int c   = (tid & 7) << 3;
        *(bf16x8*)&tile[row][c] =
            *(const bf16x8*)(hb + (size_t)(b * 2048 + n0 + row) * 128 + d0 + c);
    }
    __syncthreads();
    const int lane = tid & 63;
    const int il = lane & 15;
    const int kg = lane >> 4;
    #pragma unroll
    for (int pass = 0; pass < 2; ++pass) {
        const int f  = (tid >> 6) + (pass << 2);
        const int Dl = f >> 1;
        const int jh = f & 1;
        union { __bf16 e[8]; bf16x8 v; } u;
        #pragma unroll
        for (int e = 0; e < 8; ++e)
            u.e[e] = tile[(jh << 5) + (kg << 3) + e][(Dl << 4) + il];
        const size_t off = (((size_t)(b << 5) + (n0 >> 6)) << 13)
                         + ((size_t)((((d0 >> 4) + Dl) << 1) | jh) << 9)
                         + (lane << 3);
        *(bf16x8*)(pack + off) = u.v;
    }
}

// ---------------------------------------------------------------------------
// Kernel 4 v10: barrier-free, 1x-P fused attention partials.
// Grid 1024 = 8 batch x 32 rowgroup x 4 j-quarter; 256 thr (4 waves).
// Wave owns 16 rows x 512 j x 128 d. Lane computes the 8 P of its OWN
// A-fragment (adj read per-lane direct, 128B-chunked), B from packed global
// (coalesced 1KB, L2), f1 via LDS broadcast. 9 MFMA/step (8 PV + ones-denom).
// NO barriers in loop -> waves free-run; compiler pipelines with counted
// vmcnt. Partials: jq=0 -> out (f32); jq=1..3 -> pO (bf16); den -> pD.
// ---------------------------------------------------------------------------
__device__ __forceinline__ float pone10(float fv, int a, float C1p, float C2p) {
    float arg = fmaxf(fv + C1p, __builtin_fmaf(LRELU_ALPHA, fv, C2p));
    float mk  = (a > 0) ? 1.0f : 0.0f;
    return fexp2(__builtin_fmaf(arg, mk, -1000.f));   // masked: 2^-1000 -> 0
}

__global__ __launch_bounds__(256, 4) void gat_attn10(
    const int* __restrict__ adj, const __bf16* __restrict__ pack,
    const float* __restrict__ f1g, const float* __restrict__ f2g,
    const float* __restrict__ f1maxg,
    float* __restrict__ out, __bf16* __restrict__ pO, float* __restrict__ pD)
{
    const int bid = ((blockIdx.x & 7) << 7) | (blockIdx.x >> 3);  // batch<->XCD
    const int b  = bid >> 7;
    const int rg = (bid >> 2) & 31;
    const int jq = bid & 3;
    const int i0 = rg << 6;             // 64 rows per block
    const int jb = jq << 9;             // 512-j quarter
    const int tid = threadIdx.x;

    __shared__ float f1s[512];
    if (tid < 128)
        *(float4*)&f1s[tid << 2] = *(const float4*)&f1g[(b << 11) + jb + (tid << 2)];

    const int w    = tid >> 6;
    const int lane = tid & 63;
    const int il   = lane & 15;
    const int kg   = lane >> 4;
    const int wrow0 = i0 + (w << 4);
    const int row   = wrow0 + il;

    const float fm  = f1maxg[b];
    const float f2v = f2g[(b << 11) + row];
    const float z   = f2v + fm;
    const float M   = fmaxf(z, LRELU_ALPHA * z);      // exact bound: p <= 1
    const float C1p = f2v - M + 1000.f;
    const float C2p = __builtin_fmaf(LRELU_ALPHA, f2v, 1000.f - M);

    const int*    ap  = adj + (((size_t)(b << 11) + row) << 11) + jb + (kg << 3);
    const __bf16* pkb = pack + (((size_t)((b << 5) + (jq << 3))) << 13) + (lane << 3);

    f32x4 acc0 = {0,0,0,0}, acc1 = {0,0,0,0}, acc2 = {0,0,0,0}, acc3 = {0,0,0,0};
    f32x4 acc4 = {0,0,0,0}, acc5 = {0,0,0,0}, acc6 = {0,0,0,0}, acc7 = {0,0,0,0};
    f32x4 accd = {0,0,0,0};
    union { __bf16 e[8]; bf16x8 v; } ones;
    #pragma unroll
    for (int x = 0; x < 8; ++x) ones.e[x] = (__bf16)1.0f;
    const bf16x8 onesv = ones.v;

    // adj 1-step-ahead register pipeline (HBM latency cover)
    int4 A0c = *(const int4*)(ap);
    int4 A1c = *(const int4*)(ap + 4);

    __syncthreads();                    // f1s ready (only barrier)

    #pragma unroll 2
    for (int s = 0; s < 16; ++s) {
        const int sn = (s + 1) & 15;
        int4 A0n = *(const int4*)(ap + sn * 32);
        int4 A1n = *(const int4*)(ap + sn * 32 + 4);

        // B fragments for this step (coalesced 1KB each, L2-resident)
        const __bf16* bp = pkb + ((size_t)(s >> 1) << 13) + ((s & 1) << 9);
        bf16x8 B0 = *(const bf16x8*)(bp);
        bf16x8 B1 = *(const bf16x8*)(bp + 1024);
        bf16x8 B2 = *(const bf16x8*)(bp + 2048);
        bf16x8 B3 = *(const bf16x8*)(bp + 3072);
        bf16x8 B4 = *(const bf16x8*)(bp + 4096);
        bf16x8 B5 = *(const bf16x8*)(bp + 5120);
        bf16x8 B6 = *(const bf16x8*)(bp + 6144);
        bf16x8 B7 = *(const bf16x8*)(bp + 7168);

        const float4 fa = *(const float4*)&f1s[(s << 5) + (kg << 3)];
        const float4 fb = *(const float4*)&f1s[(s << 5) + (kg << 3) + 4];

        union { __bf16 e[8]; bf16x8 v; } pa;
        pa.e[0] = (__bf16)pone10(fa.x, A0c.x, C1p, C2p);
        pa.e[1] = (__bf16)pone10(fa.y, A0c.y, C1p, C2p);
        pa.e[2] = (__bf16)pone10(fa.z, A0c.z, C1p, C2p);
        pa.e[3] = (__bf16)pone10(fa.w, A0c.w, C1p, C2p);
        pa.e[4] = (__bf16)pone10(fb.x, A1c.x, C1p, C2p);
        pa.e[5] = (__bf16)pone10(fb.y, A1c.y, C1p, C2p);
        pa.e[6] = (__bf16)pone10(fb.z, A1c.z, C1p, C2p);
        pa.e[7] = (__bf16)pone10(fb.w, A1c.w, C1p, C2p);

        __builtin_amdgcn_s_setprio(1);
        acc0 = __builtin_amdgcn_mfma_f32_16x16x32_bf16(pa.v, B0, acc0, 0,0,0);
        acc1 = __builtin_amdgcn_mfma_f32_16x16x32_bf16(pa.v, B1, acc1, 0,0,0);
        acc2 = __builtin_amdgcn_mfma_f32_16x16x32_bf16(pa.v, B2, acc2, 0,0,0);
        acc3 = __builtin_amdgcn_mfma_f32_16x16x32_bf16(pa.v, B3, acc3, 0,0,0);
        acc4 = __builtin_amdgcn_mfma_f32_16x16x32_bf16(pa.v, B4, acc4, 0,0,0);
        acc5 = __builtin_amdgcn_mfma_f32_16x16x32_bf16(pa.v, B5, acc5, 0,0,0);
        acc6 = __builtin_amdgcn_mfma_f32_16x16x32_bf16(pa.v, B6, acc6, 0,0,0);
        acc7 = __builtin_amdgcn_mfma_f32_16x16x32_bf16(pa.v, B7, acc7, 0,0,0);
        accd = __builtin_amdgcn_mfma_f32_16x16x32_bf16(pa.v, onesv, accd, 0,0,0);
        __builtin_amdgcn_s_setprio(0);

        A0c = A0n; A1c = A1n;
    }

    // ---- write partials: C row = kg*4+r, col = il within D*16 group ----
    if (jq == 0) {
        #pragma unroll
        for (int r = 0; r < 4; ++r) {
            const size_t base = (((size_t)(b << 11) + wrow0 + (kg << 2) + r) << 7) + il;
            out[base]       = acc0[r];
            out[base +  16] = acc1[r];
            out[base +  32] = acc2[r];
            out[base +  48] = acc3[r];
            out[base +  64] = acc4[r];
            out[base +  80] = acc5[r];
            out[base +  96] = acc6[r];
            out[base + 112] = acc7[r];
        }
    } else {
        __bf16* po = pO + ((size_t)(jq - 1) << 21);
        #pragma unroll
        for (int r = 0; r < 4; ++r) {
            const size_t base = (((size_t)(b << 11) + wrow0 + (kg << 2) + r) << 7) + il;
            po[base]       = (__bf16)acc0[r];
            po[base +  16] = (__bf16)acc1[r];
            po[base +  32] = (__bf16)acc2[r];
            po[base +  48] = (__bf16)acc3[r];
            po[base +  64] = (__bf16)acc4[r];
            po[base +  80] = (__bf16)acc5[r];
            po[base +  96] = (__bf16)acc6[r];
            po[base + 112] = (__bf16)acc7[r];
        }
    }
    if (il == 0) {
        #pragma unroll
        for (int r = 0; r < 4; ++r)
            pD[(jq << 14) + (b << 11) + wrow0 + (kg << 2) + r] = accd[r];
    }
}

// ---------------------------------------------------------------------------
// Kernel 5: combine 4 j-quarter partials, normalize, elu, residual.
// io aliases out (jq=0 partial): read-before-write per element, same thread.
// ---------------------------------------------------------------------------
__global__ __launch_bounds__(256) void gat_combine(
    float* io, const __bf16* __restrict__ pO,
    const float* __restrict__ pD, const __bf16* __restrict__ hb)
{
    const int idx = blockIdx.x * 256 + threadIdx.x;    // 0..262143
    const size_t base = (size_t)idx << 3;
    const int rowAll = idx >> 4;                       // 16 threads per 128-row
    const float den = pD[rowAll] + pD[16384 + rowAll]
                    + pD[32768 + rowAll] + pD[49152 + rowAll];
    const float rden = 1.0f / den;
    float4 o0a = *(const float4*)(io + base);
    float4 o0b = *(const float4*)(io + base + 4);
    bf16x8 p1 = *(const bf16x8*)(pO + base);
    bf16x8 p2 = *(const bf16x8*)(pO + (1u << 21) + base);
    bf16x8 p3 = *(const bf16x8*)(pO + (2u << 21) + base);
    bf16x8 hv = *(const bf16x8*)(hb + base);
    float res[8];
    #pragma unroll
    for (int e = 0; e < 8; ++e) {
        float o = ((e < 4) ? ((const float*)&o0a)[e] : ((const float*)&o0b)[e - 4])
                + (float)p1[e] + (float)p2[e] + (float)p3[e];
        float v  = o * rden;
        float el = (v > 0.f) ? v : (fexp2(v * LOG2E) - 1.f);
        res[e] = el + (float)hv[e];
    }
    *(float4*)(io + base)     = (float4){res[0], res[1], res[2], res[3]};
    *(float4*)(io + base + 4) = (float4){res[4], res[5], res[6], res[7]};
}

// ---------------------------------------------------------------------------
extern "C" void kernel_launch(void* const* d_in, const int* in_sizes, int n_in,
                              void* d_out, int out_size, void* d_ws, size_t ws_size,
                              hipStream_t stream)
{
    const float* inp = (const float*)d_in[0];
    const int*   adj = (const int*)d_in[1];
    const float* W   = (const float*)d_in[2];
    const float* a   = (const float*)d_in[3];
    float* out = (float*)d_out;

    // workspace layout (~20.5 MB; d_ws is ~512 MB)
    char* ws = (char*)d_ws;
    __bf16* hb    = (__bf16*)ws;                          // 4 MB
    __bf16* pack  = (__bf16*)(ws + (4 << 20));            // 4 MB
    __bf16* pO    = (__bf16*)(ws + (8 << 20));            // 12 MB (3 bf16 partials)
    float*  pD    = (float*)(ws + (20 << 20));            // 256 KB (4 x 16384)
    float*  f1    = (float*)(ws + (20 << 20) + 262144);   // 64 KB
    float*  f2    = (float*)(ws + (20 << 20) + 262144 + 65536);
    float*  f1max = (float*)(ws + (20 << 20) + 262144 + 131072);

    gat_prep<<<2048, 128, 0, stream>>>(inp, W, a, hb, f1, f2);
    gat_f1max<<<8, 256, 0, stream>>>(f1, f1max);
    gat_pack<<<512, 256, 0, stream>>>(hb, pack);
    gat_attn10<<<1024, 256, 0, stream>>>(adj, pack, f1, f2, f1max, out, pO, pD);
    gat_combine<<<1024, 256, 0, stream>>>(out, pO, pD, hb);
}

// Round 11
// 58.676 us; speedup vs baseline: 1.2525x; 1.2525x over previous
//
#include <hip/hip_runtime.h>
#include <hip/hip_bf16.h>

typedef __bf16 bf16x8 __attribute__((ext_vector_type(8)));
typedef __bf16 bf16x4 __attribute__((ext_vector_type(4)));
typedef float  f32x4  __attribute__((ext_vector_type(4)));

#define LRELU_ALPHA 0.2f
#define LOG2E 1.44269504088896340736f

// native 2^x (single v_exp_f32, no OCML call)
__device__ __forceinline__ float fexp2(float x) {
#if __has_builtin(__builtin_amdgcn_exp2f)
    return __builtin_amdgcn_exp2f(x);
#else
    float r; asm("v_exp_f32 %0, %1" : "=v"(r) : "v"(x)); return r;
#endif
}

// raw barrier: drains LDS (lgkmcnt) but leaves global prefetches (vmcnt) in flight
__device__ __forceinline__ void wg_barrier() {
    asm volatile("s_waitcnt lgkmcnt(0)" ::: "memory");
    __builtin_amdgcn_s_barrier();
    asm volatile("" ::: "memory");
}

// ---------------------------------------------------------------------------
// Kernel 1: h = inp @ W (8 rows/block) -> hb (bf16), f1 = log2e*(h·a1),
// f2 = log2e*(h·a2).
// ---------------------------------------------------------------------------
__global__ __launch_bounds__(128) void gat_prep(
    const float* __restrict__ inp, const float* __restrict__ W,
    const float* __restrict__ a,
    __bf16* __restrict__ hb, float* __restrict__ f1, float* __restrict__ f2)
{
    const int r0 = blockIdx.x << 3;
    const int d  = threadIdx.x;
    __shared__ float sIn[8][128];
    __shared__ float sRed[8][4];
    #pragma unroll
    for (int r = 0; r < 8; ++r)
        sIn[r][d] = inp[(size_t)(r0 + r) * 128 + d];
    __syncthreads();

    float acc[8] = {0.f,0.f,0.f,0.f,0.f,0.f,0.f,0.f};
    #pragma unroll 4
    for (int k = 0; k < 128; ++k) {
        float wv = W[k * 128 + d];
        #pragma unroll
        for (int r = 0; r < 8; ++r) acc[r] += sIn[r][k] * wv;
    }

    const float a1 = a[d], a2 = a[128 + d];
    const int wv = d >> 6;
    #pragma unroll
    for (int r = 0; r < 8; ++r) {
        hb[(size_t)(r0 + r) * 128 + d] = (__bf16)acc[r];
        float t1 = acc[r] * a1;
        float t2 = acc[r] * a2;
        #pragma unroll
        for (int m = 1; m < 64; m <<= 1) {
            t1 += __shfl_xor(t1, m);
            t2 += __shfl_xor(t2, m);
        }
        if ((d & 63) == 0) { sRed[r][wv] = t1; sRed[r][2 + wv] = t2; }
    }
    __syncthreads();
    if (d < 8) {
        f1[r0 + d] = (sRed[d][0] + sRed[d][1]) * LOG2E;
        f2[r0 + d] = (sRed[d][2] + sRed[d][3]) * LOG2E;
    }
}

// ---------------------------------------------------------------------------
// Kernel 2: per-batch max of (prescaled) f1
// ---------------------------------------------------------------------------
__global__ __launch_bounds__(256) void gat_f1max(
    const float* __restrict__ f1, float* __restrict__ f1max)
{
    const int b = blockIdx.x;
    const int t = threadIdx.x;
    float m = -1e30f;
    for (int j = t; j < 2048; j += 256) m = fmaxf(m, f1[b * 2048 + j]);
    #pragma unroll
    for (int k = 1; k < 64; k <<= 1) m = fmaxf(m, __shfl_xor(m, k));
    __shared__ float sm[4];
    if ((t & 63) == 0) sm[t >> 6] = m;
    __syncthreads();
    if (t == 0) f1max[b] = fmaxf(fmaxf(sm[0], sm[1]), fmaxf(sm[2], sm[3]));
}

// ---------------------------------------------------------------------------
// Kernel 3: hb (bf16 [b][n][128]) -> pack: fragment-major bf16 B-operands.
// pack elem offset = (b*32 + jt)*8192 + frag*512 + lane*8, frag = D*2 + jh.
// Fragment lane(il,kg) elem e = h[jt*64 + jh*32 + kg*8 + e][D*16 + il].
// ---------------------------------------------------------------------------
__global__ __launch_bounds__(256) void gat_pack(
    const __bf16* __restrict__ hb, __bf16* __restrict__ pack)
{
    __shared__ __bf16 tile[64][72];
    const int tid = threadIdx.x;
    const int bidx = blockIdx.x;         // 512 blocks
    const int b  = bidx >> 6;
    const int tI = bidx & 63;
    const int n0 = (tI >> 1) << 6;       // j-range 64
    const int d0 = (tI & 1) << 6;        // d-range 64
    #pragma unroll
    for (int pass = 0; pass < 2; ++pass) {
        int row = (tid >> 3) + (pass << 5);
        int c   = (tid & 7) << 3;
        *(bf16x8*)&tile[row][c] =
            *(const bf16x8*)(hb + (size_t)(b * 2048 + n0 + row) * 128 + d0 + c);
    }
    __syncthreads();
    const int lane = tid & 63;
    const int il = lane & 15;
    const int kg = lane >> 4;
    #pragma unroll
    for (int pass = 0; pass < 2; ++pass) {
        const int f  = (tid >> 6) + (pass << 2);
        const int Dl = f >> 1;
        const int jh = f & 1;
        union { __bf16 e[8]; bf16x8 v; } u;
        #pragma unroll
        for (int e = 0; e < 8; ++e)
            u.e[e] = tile[(jh << 5) + (kg << 3) + e][(Dl << 4) + il];
        const size_t off = (((size_t)(b << 5) + (n0 >> 6)) << 13)
                         + ((size_t)((((d0 >> 4) + Dl) << 1) | jh) << 9)
                         + (lane << 3);
        *(bf16x8*)(pack + off) = u.v;
    }
}

// ---------------------------------------------------------------------------
// Kernel 4 v11: v5 structure (best measured) with EXP-FREE P computation.
// P = adj ? (u_j > ti ? ai*u_j : bi*v_j) : 0, where u=2^f1, v=2^(0.2 f1)
// (LDS tables, built in prologue) and ai=2^(f2-M), bi=2^(0.2 f2-M),
// ti=2^(-f2) per thread. Zero transcendentals in the 33.5M-element loop.
// 512 thr (8 waves = 2 ig x 4 dq); P shared via double-buffered LDS;
// one lgkm-only barrier per iteration; adj 2-deep, B 1-deep prefetch.
// ---------------------------------------------------------------------------
#define PCOMPUTE(TT, BUF) do {                                                \
    const int _jb = ((TT) << 6) + (pj4 << 2);                                 \
    float4 uu = *(const float4*)&us[_jb];                                     \
    float4 vv = *(const float4*)&vs[_jb];                                     \
    float p0 = (uu.x > ti) ? ai * uu.x : bi * vv.x;                           \
    float p1 = (uu.y > ti) ? ai * uu.y : bi * vv.y;                           \
    float p2 = (uu.z > ti) ? ai * uu.z : bi * vv.z;                           \
    float p3 = (uu.w > ti) ? ai * uu.w : bi * vv.w;                           \
    p0 = (gA.x > 0) ? p0 : 0.f;                                               \
    p1 = (gA.y > 0) ? p1 : 0.f;                                               \
    p2 = (gA.z > 0) ? p2 : 0.f;                                               \
    p3 = (gA.w > 0) ? p3 : 0.f;                                               \
    bf16x4 pb;                                                                \
    pb[0] = (__bf16)p0; pb[1] = (__bf16)p1;                                   \
    pb[2] = (__bf16)p2; pb[3] = (__bf16)p3;                                   \
    den += (float)pb[0] + (float)pb[1] + (float)pb[2] + (float)pb[3];         \
    *(bf16x4*)(&Ps[BUF][pwo]) = pb;                                           \
} while (0)

__global__ __launch_bounds__(512, 4) void gat_attn11(
    const int* __restrict__ adj, const __bf16* __restrict__ hb,
    const __bf16* __restrict__ pack, const float* __restrict__ f1g,
    const float* __restrict__ f2g, const float* __restrict__ f1maxg,
    float* __restrict__ out)
{
    const int bid = ((blockIdx.x & 7) << 6) | (blockIdx.x >> 3);  // batch<->XCD
    const int b  = bid >> 6;
    const int i0 = (bid & 63) << 5;
    const int tid = threadIdx.x;

    __shared__ float us[2048];                   // 2^f1        (8 KB)
    __shared__ float vs[2048];                   // 2^(0.2 f1)  (8 KB)
    __shared__ alignas(16) __bf16 Ps[2][2048];   // double-buffered P (32x64)
    __shared__ float lsum[32];

    {   // j-side tables: one float4 of f1 per thread -> u,v
        float4 fv = *(const float4*)&f1g[(b << 11) + (tid << 2)];
        float4 uu, vv;
        uu.x = fexp2(fv.x); uu.y = fexp2(fv.y);
        uu.z = fexp2(fv.z); uu.w = fexp2(fv.w);
        vv.x = fexp2(LRELU_ALPHA * fv.x); vv.y = fexp2(LRELU_ALPHA * fv.y);
        vv.z = fexp2(LRELU_ALPHA * fv.z); vv.w = fexp2(LRELU_ALPHA * fv.w);
        *(float4*)&us[tid << 2] = uu;
        *(float4*)&vs[tid << 2] = vv;
    }

    // ---- phase-A mapping: thread -> (row pi, j-quad pj4) ----
    const int pi  = tid >> 4;
    const int pj4 = tid & 15;
    const float fm  = f1maxg[b];
    const float f2v = f2g[(b << 11) + i0 + pi];
    const float z   = f2v + fm;
    const float M   = fmaxf(z, LRELU_ALPHA * z);          // exact bound: p <= 1
    const float ai  = fexp2(f2v - M);                     // z>0 factor
    const float bi  = fexp2(__builtin_fmaf(LRELU_ALPHA, f2v, -M)); // z<=0 factor
    const float ti  = fexp2(-f2v);                        // u_j > ti <=> z > 0
    const int* ajp = adj + (((size_t)(b << 11) + i0 + pi) << 11) + (pj4 << 2);
    const int pwo = (pi << 6) + ((((pj4 << 3)) ^ ((pi & 7) << 4)) >> 1);

    // ---- phase-B mapping: wave -> (i-group, d-quarter) ----
    const int w    = tid >> 6;
    const int lane = tid & 63;
    const int il   = lane & 15;
    const int kg   = lane >> 4;
    const int ig   = w & 1;
    const int dq   = w >> 1;
    const int ai2  = (ig << 4) + il;
    const int aof0 = (ai2 << 6) + (((kg << 4) ^ ((ai2 & 7) << 4)) >> 1);
    const int aof1 = (ai2 << 6) + (((64 | (kg << 4)) ^ ((ai2 & 7) << 4)) >> 1);
    const __bf16* pB = pack + (((size_t)b << 5) << 13) + (dq << 11) + (lane << 3);

    f32x4 acc0 = {0.f,0.f,0.f,0.f}, acc1 = {0.f,0.f,0.f,0.f};
    float den = 0.f;

    // ---- prologue ----
    int4 gA  = *(const int4*)ajp;                 // adj tile 0
    int4 gA2 = *(const int4*)(ajp + 64);          // adj tile 1
    bf16x8 Bc0 = *(const bf16x8*)(pB);            // B tile 0
    bf16x8 Bc1 = *(const bf16x8*)(pB + 512);
    bf16x8 Bc2 = *(const bf16x8*)(pB + 1024);
    bf16x8 Bc3 = *(const bf16x8*)(pB + 1536);

    wg_barrier();                                 // us/vs ready

    PCOMPUTE(0, 0);                               // P(0) -> Ps[0]
    gA = gA2;
    gA2 = *(const int4*)(ajp + 128);              // adj tile 2

    wg_barrier();                                 // Ps[0] ready

    for (int t = 0; t < 31; ++t) {
        // issue B(t+1) loads (used next iter; vmcnt stays in flight)
        const __bf16* pBn = pB + ((size_t)(t + 1) << 13);
        bf16x8 Bn0 = *(const bf16x8*)(pBn);
        bf16x8 Bn1 = *(const bf16x8*)(pBn + 512);
        bf16x8 Bn2 = *(const bf16x8*)(pBn + 1024);
        bf16x8 Bn3 = *(const bf16x8*)(pBn + 1536);

        // A-fragments of tile t (written last iter, ordered by barrier)
        bf16x8 A0 = *(const bf16x8*)(&Ps[t & 1][aof0]);
        bf16x8 A1 = *(const bf16x8*)(&Ps[t & 1][aof1]);

        // P(t+1) -> other buffer; advance adj chain
        PCOMPUTE(t + 1, (t + 1) & 1);
        gA = gA2;
        gA2 = *(const int4*)(ajp + (((t + 3) & 31) << 6));

        acc0 = __builtin_amdgcn_mfma_f32_16x16x32_bf16(A0, Bc0, acc0, 0, 0, 0);
        acc0 = __builtin_amdgcn_mfma_f32_16x16x32_bf16(A1, Bc1, acc0, 0, 0, 0);
        acc1 = __builtin_amdgcn_mfma_f32_16x16x32_bf16(A0, Bc2, acc1, 0, 0, 0);
        acc1 = __builtin_amdgcn_mfma_f32_16x16x32_bf16(A1, Bc3, acc1, 0, 0, 0);

        Bc0 = Bn0; Bc1 = Bn1; Bc2 = Bn2; Bc3 = Bn3;

        wg_barrier();                             // Ps[(t+1)&1] ready / reads done
    }

    {   // peeled t = 31
        bf16x8 A0 = *(const bf16x8*)(&Ps[1][aof0]);
        bf16x8 A1 = *(const bf16x8*)(&Ps[1][aof1]);
        acc0 = __builtin_amdgcn_mfma_f32_16x16x32_bf16(A0, Bc0, acc0, 0, 0, 0);
        acc0 = __builtin_amdgcn_mfma_f32_16x16x32_bf16(A1, Bc1, acc0, 0, 0, 0);
        acc1 = __builtin_amdgcn_mfma_f32_16x16x32_bf16(A0, Bc2, acc1, 0, 0, 0);
        acc1 = __builtin_amdgcn_mfma_f32_16x16x32_bf16(A1, Bc3, acc1, 0, 0, 0);
    }

    // ---- denominator: reduce over the 16 j-quad lanes of each row ----
    den += __shfl_xor(den, 1);
    den += __shfl_xor(den, 2);
    den += __shfl_xor(den, 4);
    den += __shfl_xor(den, 8);
    if (pj4 == 0) lsum[pi] = den;
    wg_barrier();

    // ---- epilogue: normalize, elu, residual (bf16 h) ----
    #pragma unroll
    for (int r = 0; r < 4; ++r) {
        const int   row = (kg << 2) + r;
        const float dn  = lsum[(ig << 4) + row];
        const size_t gbase = (((size_t)(b << 11) + i0 + (ig << 4) + row) << 7)
                             + (dq << 5) + il;
        float v, e;
        v = acc0[r] / dn; e = (v > 0.f) ? v : (__expf(v) - 1.f);
        out[gbase] = e + (float)hb[gbase];
        v = acc1[r] / dn; e = (v > 0.f) ? v : (__expf(v) - 1.f);
        out[gbase + 16] = e + (float)hb[gbase + 16];
    }
}

// ---------------------------------------------------------------------------
extern "C" void kernel_launch(void* const* d_in, const int* in_sizes, int n_in,
                              void* d_out, int out_size, void* d_ws, size_t ws_size,
                              hipStream_t stream)
{
    const float* inp = (const float*)d_in[0];
    const int*   adj = (const int*)d_in[1];
    const float* W   = (const float*)d_in[2];
    const float* a   = (const float*)d_in[3];
    float* out = (float*)d_out;

    // workspace layout (~8.2 MB)
    char* ws = (char*)d_ws;
    __bf16* hb    = (__bf16*)ws;                       // 4 MB
    __bf16* pack  = (__bf16*)(ws + (4 << 20));         // 4 MB
    float*  f1    = (float*)(ws + (8 << 20));          // 64 KB
    float*  f2    = (float*)(ws + (8 << 20) + 65536);
    float*  f1max = (float*)(ws + (8 << 20) + 131072);

    gat_prep<<<2048, 128, 0, stream>>>(inp, W, a, hb, f1, f2);
    gat_f1max<<<8, 256, 0, stream>>>(f1, f1max);
    gat_pack<<<512, 256, 0, stream>>>(hb, pack);
    gat_attn11<<<512, 512, 0, stream>>>(adj, hb, pack, f1, f2, f1max, out);
}